// Round 3
// baseline (3262.097 us; speedup 1.0000x reference)
//
#include <hip/hip_runtime.h>
#include <hip/hip_fp16.h>

typedef _Float16 half8 __attribute__((ext_vector_type(8)));
typedef float floatx4 __attribute__((ext_vector_type(4)));

// d_ws half-element layout (packed fragment-major, hi then lo per layer)
#define W1H_OFF 0
#define W1L_OFF 32768
#define W2H_OFF 65536
#define W2L_OFF 131072
#define W3H_OFF 196608
#define W3L_OFF 212992

__device__ __forceinline__ floatx4 mfma16(half8 a, half8 b, floatx4 c) {
    return __builtin_amdgcn_mfma_f32_16x16x32_f16(a, b, c, 0, 0, 0);
}

// Pack W[n][k] (row-major [N][K] fp32) into MFMA-B fragment-major fp16 hi/lo
__global__ __launch_bounds__(256) void pack_weights(
    const float* __restrict__ W1, const float* __restrict__ W2,
    const float* __restrict__ W3, _Float16* __restrict__ ws)
{
    int e = blockIdx.x * 256 + threadIdx.x;  // 0..114687
    const float* W;
    int K, NT, hoff, loff, eb = e;
    if (e < 32768)      { W = W1; K = 128; NT = 16; hoff = W1H_OFF; loff = W1L_OFF; }
    else if (e < 98304) { W = W2; K = 256; NT = 16; hoff = W2H_OFF; loff = W2L_OFF; eb = e - 32768; }
    else                { W = W3; K = 256; NT = 4;  hoff = W3H_OFF; loff = W3L_OFF; eb = e - 98304; }
    int j = eb & 7, l = (eb >> 3) & 63, t = eb >> 9;
    int tn = t % NT, kk = t / NT;
    int n = tn * 16 + (l & 15);
    int k = kk * 32 + ((l >> 4) * 8) + j;
    float wv = W[n * K + k];
    _Float16 hi = (_Float16)wv;
    _Float16 lo = (_Float16)(wv - (float)hi);
    ws[hoff + eb] = hi;
    ws[loff + eb] = lo;
}

// swizzled LDS activation fragment read: element idx = (row*K + k0) ^ ((row&7)<<3)
__device__ __forceinline__ half8 lds_frag(const _Float16* s, int K, int row, int k0) {
    int idx = (row * K + k0) ^ ((row & 7) << 3);
    return *reinterpret_cast<const half8*>(s + idx);
}

__global__ __launch_bounds__(1024) void ode_kernel(
    const float* __restrict__ x0, const float* __restrict__ u,
    const float* __restrict__ b1, const float* __restrict__ b2,
    const float* __restrict__ b3, const _Float16* __restrict__ ws,
    const int* __restrict__ t0p, const int* __restrict__ t1p,
    float* __restrict__ out)
{
    __shared__ _Float16 sW1h[32768];           // 64 KB: W1-hi packed fragment-major
    __shared__ _Float16 sW3h[16384];           // 32 KB: W3-hi packed
    __shared__ _Float16 sA1h[4096], sA1l[4096];
    __shared__ _Float16 sA2h[4096], sA2l[4096];
    __shared__ _Float16 sZh[2048], sZl[2048];
    __shared__ float sKf[5 * 1024];            // k1..k5 in C-frag positions
    // total LDS = 65536+32768+32768+8192+20480 = 159744 B (1 block/CU)

    const int tid = threadIdx.x;
    const int lane = tid & 63;
    const int w = tid >> 6;           // wave 0..15; owns N-tile w (cols 16w..16w+15)
    const int r0 = blockIdx.x * 16;

    // ---- stage W1-hi / W3-hi into LDS ----
    {
        const half8* s1 = reinterpret_cast<const half8*>(ws + W1H_OFF);
        half8* d1 = reinterpret_cast<half8*>(sW1h);
        #pragma unroll
        for (int i = 0; i < 4; ++i) d1[tid + 1024 * i] = s1[tid + 1024 * i];
        const half8* s3 = reinterpret_cast<const half8*>(ws + W3H_OFF);
        half8* d3 = reinterpret_cast<half8*>(sW3h);
        #pragma unroll
        for (int i = 0; i < 2; ++i) d3[tid + 1024 * i] = s3[tid + 1024 * i];
    }
    // ---- resident weights: W2-hi (1 tile/wave) + W1-lo (1 tile/wave) ----
    half8 rW2h[8], rW1l[4];
    {
        const half8* g2h = reinterpret_cast<const half8*>(ws + W2H_OFF);
        const half8* g1l = reinterpret_cast<const half8*>(ws + W1L_OFF);
        #pragma unroll
        for (int kk = 0; kk < 8; ++kk)
            rW2h[kk] = g2h[(kk * 16 + w) * 64 + lane];
        #pragma unroll
        for (int kk = 0; kk < 4; ++kk)
            rW1l[kk] = g1l[(kk * 16 + w) * 64 + lane];
    }
    const float rB1 = b1[16 * w + (lane & 15)];
    const float rB2 = b2[16 * w + (lane & 15)];
    const float rB3 = (w < 4) ? b3[16 * w + (lane & 15)] : 0.f;

    const int q4 = (lane >> 4) * 4;
    const int ocol = 16 * (w & 3) + (lane & 15);  // L3 C-frag col (valid on w<4)

    // y state in C-frag registers (meaningful on w<4)
    float yv[4];
    #pragma unroll
    for (int r = 0; r < 4; ++r)
        yv[r] = x0[(r0 + q4 + r) * 64 + ((w < 4) ? ocol : 0)];

    // Z init (threads 0-511): z = y0 | u, fp16 hi/lo, swizzled
    if (tid < 512) {
        int row = tid >> 5, c0 = (tid & 31) * 2;
        float y0v = x0[(r0 + row) * 64 + c0], y1v = x0[(r0 + row) * 64 + c0 + 1];
        float u0v = u[(r0 + row) * 64 + c0], u1v = u[(r0 + row) * 64 + c0 + 1];
        int zy = (row * 128 + c0) ^ ((row & 7) << 3);
        int zu = (row * 128 + 64 + c0) ^ ((row & 7) << 3);
        _Float16 h0 = (_Float16)y0v, h1 = (_Float16)y1v;
        sZh[zy] = h0; sZh[zy + 1] = h1;
        sZl[zy] = (_Float16)(y0v - (float)h0);
        sZl[zy + 1] = (_Float16)(y1v - (float)h1);
        _Float16 g0 = (_Float16)u0v, g1 = (_Float16)u1v;
        sZh[zu] = g0; sZh[zu + 1] = g1;
        sZl[zu] = (_Float16)(u0v - (float)g0);
        sZl[zu + 1] = (_Float16)(u1v - (float)g1);
    }
    __syncthreads();

    const int nsteps = (t1p[0] - t0p[0]) * 60;  // h = 60s = 1/60 hr
    const float H = 1.0f / 60.0f;
    const int arow = lane & 15;
    const int kb = (lane >> 4) * 8;

    const half8* g2l = reinterpret_cast<const half8*>(ws + W2L_OFF);
    const half8* g3l = reinterpret_cast<const half8*>(ws + W3L_OFF);

    // Tsitouras 5(4) coefficients as compile-time constants (stage loop unrolled)
    constexpr float CF[6][6] = {
        {0.161f, 0.f, 0.f, 0.f, 0.f, 0.f},
        {-0.008480655492356989f, 0.335480655492357f, 0.f, 0.f, 0.f, 0.f},
        {2.8971530571054935f, -6.359448489975075f, 4.3622954328695815f, 0.f, 0.f, 0.f},
        {5.325864828439257f, -11.748883564062828f, 7.4955393428898365f, -0.09249506636175525f, 0.f, 0.f},
        {5.86145544294642f, -12.92096931784711f, 8.159367898576159f, -0.071584973281401f, -0.028269050394068383f, 0.f},
        {0.09646076681806523f, 0.01f, 0.4798896504144996f, 1.379008574103742f, -3.290069515436081f, 2.324710524099774f},
    };

    #pragma unroll 1
    for (int step = 0; step < nsteps; ++step) {
        #pragma unroll
        for (int stg = 0; stg < 6; ++stg) {
            // ---- stream this wave's W2-lo tile (used in L2; latency hides under L1) ----
            half8 wl2[8];
            #pragma unroll
            for (int kk = 0; kk < 8; ++kk)
                wl2[kk] = g2l[(kk * 16 + w) * 64 + lane];

            // ---------- Layer 1: z[16x128] @ W1^T -> relu -> sA1 ----------
            {
                floatx4 a0 = floatx4{rB1, rB1, rB1, rB1};
                floatx4 a1 = floatx4{0.f, 0.f, 0.f, 0.f};
                #pragma unroll
                for (int kk = 0; kk < 4; ++kk) {
                    half8 ah = lds_frag(sZh, 128, arow, kb + kk * 32);
                    half8 al = lds_frag(sZl, 128, arow, kb + kk * 32);
                    half8 bh = *reinterpret_cast<const half8*>(
                        sW1h + ((kk * 16 + w) * 64 + lane) * 8);
                    floatx4& ac = (kk & 1) ? a1 : a0;
                    ac = mfma16(ah, bh, ac);
                    ac = mfma16(ah, rW1l[kk], ac);
                    ac = mfma16(al, bh, ac);
                }
                int col = 16 * w + (lane & 15);
                #pragma unroll
                for (int r = 0; r < 4; ++r) {
                    int orow = q4 + r;
                    float v = fmaxf(a0[r] + a1[r], 0.f);
                    _Float16 hi = (_Float16)v, lo = (_Float16)(v - (float)hi);
                    int idx = (orow * 256 + col) ^ ((orow & 7) << 3);
                    sA1h[idx] = hi;
                    sA1l[idx] = lo;
                }
            }
            __syncthreads();
            // ---------- Layer 2: a1[16x256] @ W2^T -> relu -> sA2 ----------
            {
                floatx4 a0 = floatx4{rB2, rB2, rB2, rB2};
                floatx4 a1 = floatx4{0.f, 0.f, 0.f, 0.f};
                #pragma unroll
                for (int kk = 0; kk < 8; ++kk) {
                    half8 ah = lds_frag(sA1h, 256, arow, kb + kk * 32);
                    half8 al = lds_frag(sA1l, 256, arow, kb + kk * 32);
                    floatx4& ac = (kk & 1) ? a1 : a0;
                    ac = mfma16(ah, rW2h[kk], ac);
                    ac = mfma16(ah, wl2[kk], ac);
                    ac = mfma16(al, rW2h[kk], ac);
                }
                // stream this wave's W3-lo tile now (used next phase, w<4 only)
                half8 wl3[8];
                if (w < 4) {
                    #pragma unroll
                    for (int kk = 0; kk < 8; ++kk)
                        wl3[kk] = g3l[(kk * 4 + w) * 64 + lane];
                }
                int col = 16 * w + (lane & 15);
                #pragma unroll
                for (int r = 0; r < 4; ++r) {
                    int orow = q4 + r;
                    float v = fmaxf(a0[r] + a1[r], 0.f);
                    _Float16 hi = (_Float16)v, lo = (_Float16)(v - (float)hi);
                    int idx = (orow * 256 + col) ^ ((orow & 7) << 3);
                    sA2h[idx] = hi;
                    sA2l[idx] = lo;
                }
                __syncthreads();
                // ---------- Layer 3 + RK combine (waves 0-3) ----------
                if (w < 4) {
                    floatx4 aE = floatx4{rB3, rB3, rB3, rB3};
                    floatx4 aO = floatx4{0.f, 0.f, 0.f, 0.f};
                    #pragma unroll
                    for (int kk = 0; kk < 8; ++kk) {
                        half8 ah = lds_frag(sA2h, 256, arow, kb + kk * 32);
                        half8 al = lds_frag(sA2l, 256, arow, kb + kk * 32);
                        half8 bh = *reinterpret_cast<const half8*>(
                            sW3h + ((kk * 4 + w) * 64 + lane) * 8);
                        floatx4& ac = (kk & 1) ? aO : aE;
                        ac = mfma16(ah, bh, ac);
                        ac = mfma16(ah, wl3[kk], ac);
                        ac = mfma16(al, bh, ac);
                    }
                    // combine: z = y + H*(sum_{j<stg} c_j*k_j + c_stg*k_new)
                    #pragma unroll
                    for (int r = 0; r < 4; ++r) {
                        int orow = q4 + r;
                        float kc = aE[r] + aO[r];
                        float s = CF[stg][stg] * kc;
                        #pragma unroll
                        for (int j = 0; j < stg; ++j)
                            s += CF[stg][j] * sKf[j * 1024 + orow * 64 + ocol];
                        float z = yv[r] + H * s;
                        if (stg < 5) sKf[stg * 1024 + orow * 64 + ocol] = kc;
                        else yv[r] = z;  // final combine of the step
                        int idx = (orow * 128 + ocol) ^ ((orow & 7) << 3);
                        _Float16 h0 = (_Float16)z;
                        sZh[idx] = h0;
                        sZl[idx] = (_Float16)(z - (float)h0);
                    }
                }
            }
            __syncthreads();
        }
    }
    // ---- write y_final from registers ----
    if (w < 4) {
        #pragma unroll
        for (int r = 0; r < 4; ++r)
            out[(r0 + q4 + r) * 64 + ocol] = yv[r];
    }
}

extern "C" void kernel_launch(void* const* d_in, const int* in_sizes, int n_in,
                              void* d_out, int out_size, void* d_ws, size_t ws_size,
                              hipStream_t stream)
{
    const float* x0 = (const float*)d_in[0];
    const float* u  = (const float*)d_in[1];
    const float* W1 = (const float*)d_in[2];
    const float* b1 = (const float*)d_in[3];
    const float* W2 = (const float*)d_in[4];
    const float* b2 = (const float*)d_in[5];
    const float* W3 = (const float*)d_in[6];
    const float* b3 = (const float*)d_in[7];
    const int* t0 = (const int*)d_in[8];
    const int* t1 = (const int*)d_in[9];
    float* out = (float*)d_out;
    _Float16* ws = (_Float16*)d_ws;

    pack_weights<<<448, 256, 0, stream>>>(W1, W2, W3, ws);
    ode_kernel<<<64, 1024, 0, stream>>>(x0, u, b1, b2, b3, ws, t0, t1, out);
}

// Round 4
// 2182.225 us; speedup vs baseline: 1.4948x; 1.4948x over previous
//
#include <hip/hip_runtime.h>
#include <hip/hip_fp16.h>

typedef _Float16 half8 __attribute__((ext_vector_type(8)));
typedef float floatx4 __attribute__((ext_vector_type(4)));

// d_ws half-element layout (packed fragment-major fp16)
#define W1YH_OFF 0        // W1 y-half (K=0..63)  hi: 256x64
#define W1YL_OFF 16384    //                      lo
#define W1UH_OFF 32768    // W1 u-half (K=64..127) hi
#define W1UL_OFF 49152    //                       lo
#define W2H_OFF  65536    // W2 hi: 256x256
#define W2L_OFF  131072
#define W3H_OFF  196608   // W3 hi: 64x256
#define W3L_OFF  212992
// total = 229376 halfs (448 KB)

__device__ __forceinline__ floatx4 mfma16(half8 a, half8 b, floatx4 c) {
    return __builtin_amdgcn_mfma_f32_16x16x32_f16(a, b, c, 0, 0, 0);
}

// Pack W[n][k] (row-major [N][K] fp32) into MFMA-B fragment-major fp16 hi/lo
__global__ __launch_bounds__(256) void pack_weights(
    const float* __restrict__ W1, const float* __restrict__ W2,
    const float* __restrict__ W3, _Float16* __restrict__ ws)
{
    int e = blockIdx.x * 256 + threadIdx.x;  // 0..114687
    const float* W;
    int K, NT, eb = e;
    if (e < 32768)      { W = W1; K = 128; NT = 16; }
    else if (e < 98304) { W = W2; K = 256; NT = 16; eb = e - 32768; }
    else                { W = W3; K = 256; NT = 4;  eb = e - 98304; }
    int j = eb & 7, l = (eb >> 3) & 63, t = eb >> 9;
    int tn = t % NT, kk = t / NT;
    int n = tn * 16 + (l & 15);
    int k = kk * 32 + ((l >> 4) * 8) + j;
    float wv = W[n * K + k];
    _Float16 hi = (_Float16)wv;
    _Float16 lo = (_Float16)(wv - (float)hi);
    int hoff, loff, fi;
    if (e < 32768) {            // W1: split y-half (kk<2) / u-half (kk>=2)
        if (kk < 2) { hoff = W1YH_OFF; loff = W1YL_OFF; fi = ((kk * 16 + tn) * 64 + l) * 8 + j; }
        else        { hoff = W1UH_OFF; loff = W1UL_OFF; fi = (((kk - 2) * 16 + tn) * 64 + l) * 8 + j; }
    } else if (e < 98304) { hoff = W2H_OFF; loff = W2L_OFF; fi = eb; }
    else                  { hoff = W3H_OFF; loff = W3L_OFF; fi = eb; }
    ws[hoff + fi] = hi;
    ws[loff + fi] = lo;
}

// swizzled LDS activation fragment read: element idx = (row*K + k0) ^ ((row&7)<<3)
__device__ __forceinline__ half8 lds_frag(const _Float16* s, int K, int row, int k0) {
    int idx = (row * K + k0) ^ ((row & 7) << 3);
    return *reinterpret_cast<const half8*>(s + idx);
}

__global__ __launch_bounds__(1024, 4) void ode_kernel(
    const float* __restrict__ x0, const float* __restrict__ u,
    const float* __restrict__ b1, const float* __restrict__ b2,
    const float* __restrict__ b3, const _Float16* __restrict__ ws,
    const int* __restrict__ t0p, const int* __restrict__ t1p,
    float* __restrict__ out)
{
    __shared__ _Float16 sW3h[16384], sW3l[16384];  // 32K + 32K
    __shared__ _Float16 sA1h[4096], sA1l[4096];    // 8K + 8K
    __shared__ _Float16 sA2h[4096], sA2l[4096];    // 8K + 8K
    __shared__ _Float16 sZh[1024], sZl[1024];      // 2K + 2K (y-half only)
    __shared__ float sKf[5 * 1024];                // 20K: k1..k5 C-frag layout
    // total LDS = 122880 B

    const int tid = threadIdx.x;
    const int lane = tid & 63;
    const int w = tid >> 6;            // wave 0..15; owns N-tile w
    const int r0 = blockIdx.x * 16;
    const int arow = lane & 15;
    const int kb = (lane >> 4) * 8;
    const int q4 = (lane >> 4) * 4;
    const int ncol = 16 * w + (lane & 15);        // this wave's output col (H dim)
    const int ocol = 16 * (w & 3) + (lane & 15);  // L3 C-frag col (valid for w<4)

    // ---- stage W3 hi/lo into LDS (one-time) ----
    {
        const half8* s3h = reinterpret_cast<const half8*>(ws + W3H_OFF);
        const half8* s3l = reinterpret_cast<const half8*>(ws + W3L_OFF);
        half8* d3h = reinterpret_cast<half8*>(sW3h);
        half8* d3l = reinterpret_cast<half8*>(sW3l);
        #pragma unroll
        for (int i = 0; i < 2; ++i) {
            d3h[tid + 1024 * i] = s3h[tid + 1024 * i];
            d3l[tid + 1024 * i] = s3l[tid + 1024 * i];
        }
    }
    // ---- register-resident weights: W2 tile (hi+lo) + W1y tile (hi+lo) ----
    half8 rW2h[8], rW2l[8], rW1h[2], rW1l[2];
    {
        const half8* g2h = reinterpret_cast<const half8*>(ws + W2H_OFF);
        const half8* g2l = reinterpret_cast<const half8*>(ws + W2L_OFF);
        const half8* g1h = reinterpret_cast<const half8*>(ws + W1YH_OFF);
        const half8* g1l = reinterpret_cast<const half8*>(ws + W1YL_OFF);
        #pragma unroll
        for (int kk = 0; kk < 8; ++kk) {
            rW2h[kk] = g2h[(kk * 16 + w) * 64 + lane];
            rW2l[kk] = g2l[(kk * 16 + w) * 64 + lane];
        }
        #pragma unroll
        for (int kk = 0; kk < 2; ++kk) {
            rW1h[kk] = g1h[(kk * 16 + w) * 64 + lane];
            rW1l[kk] = g1l[(kk * 16 + w) * 64 + lane];
        }
    }
    const float rB2 = b2[ncol];
    const float rB3 = b3[ocol];  // only used on w<4

    // y state in C-frag registers (meaningful on w<4)
    float yv[4];
    #pragma unroll
    for (int r = 0; r < 4; ++r)
        yv[r] = x0[(r0 + q4 + r) * 64 + ocol];

    // ---- stage u (hi/lo, swizzled) into sA1 temporarily; z-y into sZ ----
    if (tid < 512) {
        int row = tid >> 5, c0 = (tid & 31) * 2;
        float u0v = u[(r0 + row) * 64 + c0], u1v = u[(r0 + row) * 64 + c0 + 1];
        float y0v = x0[(r0 + row) * 64 + c0], y1v = x0[(r0 + row) * 64 + c0 + 1];
        int idx = (row * 64 + c0) ^ ((row & 7) << 3);
        _Float16 g0 = (_Float16)u0v, g1 = (_Float16)u1v;
        sA1h[idx] = g0; sA1h[idx + 1] = g1;
        sA1l[idx] = (_Float16)(u0v - (float)g0);
        sA1l[idx + 1] = (_Float16)(u1v - (float)g1);
        _Float16 h0 = (_Float16)y0v, h1 = (_Float16)y1v;
        sZh[idx] = h0; sZh[idx + 1] = h1;
        sZl[idx] = (_Float16)(y0v - (float)h0);
        sZl[idx + 1] = (_Float16)(y1v - (float)h1);
    }
    __syncthreads();

    // ---- precompute cU = u @ W1u^T + b1 (per-lane C fragment, 4 regs) ----
    float cU[4];
    {
        float b1v = b1[ncol];
        floatx4 a0 = floatx4{b1v, b1v, b1v, b1v};
        floatx4 a1 = floatx4{0.f, 0.f, 0.f, 0.f};
        const half8* guh = reinterpret_cast<const half8*>(ws + W1UH_OFF);
        const half8* gul = reinterpret_cast<const half8*>(ws + W1UL_OFF);
        #pragma unroll
        for (int kk = 0; kk < 2; ++kk) {
            half8 ah = lds_frag(sA1h, 64, arow, kb + kk * 32);
            half8 al = lds_frag(sA1l, 64, arow, kb + kk * 32);
            half8 bh = guh[(kk * 16 + w) * 64 + lane];
            half8 bl = gul[(kk * 16 + w) * 64 + lane];
            floatx4& ac = kk ? a1 : a0;
            ac = mfma16(ah, bh, ac);
            ac = mfma16(ah, bl, ac);
            ac = mfma16(al, bh, ac);
        }
        #pragma unroll
        for (int r = 0; r < 4; ++r) cU[r] = a0[r] + a1[r];
    }
    __syncthreads();  // done using sA1 as u-staging

    const int nsteps = (t1p[0] - t0p[0]) * 60;  // h = 60s = 1/60 hr
    const float H = 1.0f / 60.0f;

    // Tsitouras 5(4) coefficients (stage loop unrolled -> immediates)
    constexpr float CF[6][6] = {
        {0.161f, 0.f, 0.f, 0.f, 0.f, 0.f},
        {-0.008480655492356989f, 0.335480655492357f, 0.f, 0.f, 0.f, 0.f},
        {2.8971530571054935f, -6.359448489975075f, 4.3622954328695815f, 0.f, 0.f, 0.f},
        {5.325864828439257f, -11.748883564062828f, 7.4955393428898365f, -0.09249506636175525f, 0.f, 0.f},
        {5.86145544294642f, -12.92096931784711f, 8.159367898576159f, -0.071584973281401f, -0.028269050394068383f, 0.f},
        {0.09646076681806523f, 0.01f, 0.4798896504144996f, 1.379008574103742f, -3.290069515436081f, 2.324710524099774f},
    };

    #pragma unroll 1
    for (int step = 0; step < nsteps; ++step) {
        #pragma unroll
        for (int stg = 0; stg < 6; ++stg) {
            // ---------- Layer 1: z_y[16x64] @ W1y^T + cU -> relu -> sA1 ----------
            {
                floatx4 a0 = floatx4{cU[0], cU[1], cU[2], cU[3]};
                floatx4 a1 = floatx4{0.f, 0.f, 0.f, 0.f};
                #pragma unroll
                for (int kk = 0; kk < 2; ++kk) {
                    half8 ah = lds_frag(sZh, 64, arow, kb + kk * 32);
                    half8 al = lds_frag(sZl, 64, arow, kb + kk * 32);
                    floatx4& ac = kk ? a1 : a0;
                    ac = mfma16(ah, rW1h[kk], ac);
                    ac = mfma16(ah, rW1l[kk], ac);
                    ac = mfma16(al, rW1h[kk], ac);
                }
                #pragma unroll
                for (int r = 0; r < 4; ++r) {
                    int orow = q4 + r;
                    float v = fmaxf(a0[r] + a1[r], 0.f);
                    _Float16 hi = (_Float16)v, lo = (_Float16)(v - (float)hi);
                    int idx = (orow * 256 + ncol) ^ ((orow & 7) << 3);
                    sA1h[idx] = hi;
                    sA1l[idx] = lo;
                }
            }
            __syncthreads();
            // ---------- Layer 2: a1[16x256] @ W2^T -> relu -> sA2 (W2 in regs) ----------
            {
                floatx4 a0 = floatx4{rB2, rB2, rB2, rB2};
                floatx4 a1 = floatx4{0.f, 0.f, 0.f, 0.f};
                #pragma unroll
                for (int kk = 0; kk < 8; ++kk) {
                    half8 ah = lds_frag(sA1h, 256, arow, kb + kk * 32);
                    half8 al = lds_frag(sA1l, 256, arow, kb + kk * 32);
                    floatx4& ac = (kk & 1) ? a1 : a0;
                    ac = mfma16(ah, rW2h[kk], ac);
                    ac = mfma16(ah, rW2l[kk], ac);
                    ac = mfma16(al, rW2h[kk], ac);
                }
                #pragma unroll
                for (int r = 0; r < 4; ++r) {
                    int orow = q4 + r;
                    float v = fmaxf(a0[r] + a1[r], 0.f);
                    _Float16 hi = (_Float16)v, lo = (_Float16)(v - (float)hi);
                    int idx = (orow * 256 + ncol) ^ ((orow & 7) << 3);
                    sA2h[idx] = hi;
                    sA2l[idx] = lo;
                }
            }
            __syncthreads();
            // ---------- Layer 3 + RK combine (waves 0-3) ----------
            if (w < 4) {
                floatx4 a0 = floatx4{rB3, rB3, rB3, rB3};
                floatx4 a1 = floatx4{0.f, 0.f, 0.f, 0.f};
                #pragma unroll
                for (int kk = 0; kk < 8; ++kk) {
                    half8 ah = lds_frag(sA2h, 256, arow, kb + kk * 32);
                    half8 al = lds_frag(sA2l, 256, arow, kb + kk * 32);
                    half8 bh = *reinterpret_cast<const half8*>(
                        sW3h + ((kk * 4 + w) * 64 + lane) * 8);
                    half8 bl = *reinterpret_cast<const half8*>(
                        sW3l + ((kk * 4 + w) * 64 + lane) * 8);
                    floatx4& ac = (kk & 1) ? a1 : a0;
                    ac = mfma16(ah, bh, ac);
                    ac = mfma16(ah, bl, ac);
                    ac = mfma16(al, bh, ac);
                }
                // combine: z = y + H*(sum_{j<stg} c_j*k_j + c_stg*k_new)
                #pragma unroll
                for (int r = 0; r < 4; ++r) {
                    int orow = q4 + r;
                    float kc = a0[r] + a1[r];
                    float s = CF[stg][stg] * kc;
                    #pragma unroll
                    for (int j = 0; j < stg; ++j)
                        s += CF[stg][j] * sKf[j * 1024 + orow * 64 + ocol];
                    float z = yv[r] + H * s;
                    if (stg < 5) sKf[stg * 1024 + orow * 64 + ocol] = kc;
                    else yv[r] = z;  // final combine of the step
                    int idx = (orow * 64 + ocol) ^ ((orow & 7) << 3);
                    _Float16 h0 = (_Float16)z;
                    sZh[idx] = h0;
                    sZl[idx] = (_Float16)(z - (float)h0);
                }
            }
            __syncthreads();
        }
    }
    // ---- write y_final from registers ----
    if (w < 4) {
        #pragma unroll
        for (int r = 0; r < 4; ++r)
            out[(r0 + q4 + r) * 64 + ocol] = yv[r];
    }
}

extern "C" void kernel_launch(void* const* d_in, const int* in_sizes, int n_in,
                              void* d_out, int out_size, void* d_ws, size_t ws_size,
                              hipStream_t stream)
{
    const float* x0 = (const float*)d_in[0];
    const float* u  = (const float*)d_in[1];
    const float* W1 = (const float*)d_in[2];
    const float* b1 = (const float*)d_in[3];
    const float* W2 = (const float*)d_in[4];
    const float* b2 = (const float*)d_in[5];
    const float* W3 = (const float*)d_in[6];
    const float* b3 = (const float*)d_in[7];
    const int* t0 = (const int*)d_in[8];
    const int* t1 = (const int*)d_in[9];
    float* out = (float*)d_out;
    _Float16* ws = (_Float16*)d_ws;

    pack_weights<<<448, 256, 0, stream>>>(W1, W2, W3, ws);
    ode_kernel<<<64, 1024, 0, stream>>>(x0, u, b1, b2, b3, ws, t0, t1, out);
}

// Round 5
// 1029.794 us; speedup vs baseline: 3.1677x; 2.1191x over previous
//
#include <hip/hip_runtime.h>
#include <hip/hip_fp16.h>

typedef _Float16 half8 __attribute__((ext_vector_type(8)));
typedef float floatx4 __attribute__((ext_vector_type(4)));

// d_ws half-element layout (packed fragment-major fp16)
#define W1YH_OFF 0        // W1 y-half (K=0..63)  hi: 256x64
#define W1YL_OFF 16384    //                      lo
#define W1UH_OFF 32768    // W1 u-half (K=64..127) hi
#define W1UL_OFF 49152    //                       lo
#define W2H_OFF  65536    // W2 hi: 256x256
#define W2L_OFF  131072
#define W3H_OFF  196608   // W3 hi: 64x256
#define W3L_OFF  212992

__device__ __forceinline__ floatx4 mfma16(half8 a, half8 b, floatx4 c) {
    return __builtin_amdgcn_mfma_f32_16x16x32_f16(a, b, c, 0, 0, 0);
}

// Pack W[n][k] (row-major [N][K] fp32) into MFMA-B fragment-major fp16 hi/lo
__global__ __launch_bounds__(256) void pack_weights(
    const float* __restrict__ W1, const float* __restrict__ W2,
    const float* __restrict__ W3, _Float16* __restrict__ ws)
{
    int e = blockIdx.x * 256 + threadIdx.x;  // 0..114687
    const float* W;
    int K, NT, eb = e;
    if (e < 32768)      { W = W1; K = 128; NT = 16; }
    else if (e < 98304) { W = W2; K = 256; NT = 16; eb = e - 32768; }
    else                { W = W3; K = 256; NT = 4;  eb = e - 98304; }
    int j = eb & 7, l = (eb >> 3) & 63, t = eb >> 9;
    int tn = t % NT, kk = t / NT;
    int n = tn * 16 + (l & 15);
    int k = kk * 32 + ((l >> 4) * 8) + j;
    float wv = W[n * K + k];
    _Float16 hi = (_Float16)wv;
    _Float16 lo = (_Float16)(wv - (float)hi);
    int hoff, loff, fi;
    if (e < 32768) {            // W1: split y-half (kk<2) / u-half (kk>=2)
        if (kk < 2) { hoff = W1YH_OFF; loff = W1YL_OFF; fi = ((kk * 16 + tn) * 64 + l) * 8 + j; }
        else        { hoff = W1UH_OFF; loff = W1UL_OFF; fi = (((kk - 2) * 16 + tn) * 64 + l) * 8 + j; }
    } else if (e < 98304) { hoff = W2H_OFF; loff = W2L_OFF; fi = eb; }
    else                  { hoff = W3H_OFF; loff = W3L_OFF; fi = eb; }
    ws[hoff + fi] = hi;
    ws[loff + fi] = lo;
}

// swizzled LDS activation fragment read: element idx = (row*K + k0) ^ ((row&7)<<3)
__device__ __forceinline__ half8 lds_frag(const _Float16* s, int K, int row, int k0) {
    int idx = (row * K + k0) ^ ((row & 7) << 3);
    return *reinterpret_cast<const half8*>(s + idx);
}

__global__ __launch_bounds__(512) void ode_kernel(
    const float* __restrict__ x0, const float* __restrict__ u,
    const float* __restrict__ b1, const float* __restrict__ b2,
    const float* __restrict__ b3, const _Float16* __restrict__ ws,
    const int* __restrict__ t0p, const int* __restrict__ t1p,
    float* __restrict__ out)
{
    __shared__ _Float16 sW3h[16384], sW3l[16384];  // 32K + 32K
    __shared__ _Float16 sW1yh[16384];              // 32K
    __shared__ _Float16 sA1h[4096], sA1l[4096];    // 8K + 8K
    __shared__ _Float16 sA2h[4096], sA2l[4096];    // 8K + 8K
    __shared__ _Float16 sZh[1024], sZl[1024];      // 2K + 2K
    __shared__ float sKf[5120];                    // 20K: k1..k5 C-frag layout
    // total LDS = 155648 B

    const int tid = threadIdx.x;
    const int lane = tid & 63;
    const int w = tid >> 6;            // wave 0..7; owns N-tiles {2w, 2w+1}
    const int r0 = blockIdx.x * 16;
    const int arow = lane & 15;
    const int kb = (lane >> 4) * 8;
    const int q4 = (lane >> 4) * 4;
    const int t0n = 2 * w, t1n = 2 * w + 1;
    const int col0 = 16 * t0n + arow, col1 = 16 * t1n + arow;
    const int ocol = 16 * (w & 3) + arow;   // L3 C-frag col (valid on w<4)

    // ---- one-time LDS staging: W3 hi/lo + W1y hi (6144 half8) ----
    {
        const half8* s3h = reinterpret_cast<const half8*>(ws + W3H_OFF);
        const half8* s3l = reinterpret_cast<const half8*>(ws + W3L_OFF);
        const half8* s1h = reinterpret_cast<const half8*>(ws + W1YH_OFF);
        half8* d3h = reinterpret_cast<half8*>(sW3h);
        half8* d3l = reinterpret_cast<half8*>(sW3l);
        half8* d1h = reinterpret_cast<half8*>(sW1yh);
        #pragma unroll
        for (int i = 0; i < 4; ++i) {
            d3h[tid + 512 * i] = s3h[tid + 512 * i];
            d3l[tid + 512 * i] = s3l[tid + 512 * i];
            d1h[tid + 512 * i] = s1h[tid + 512 * i];
        }
    }
    // ---- resident W2-lo (own 2 N-tiles) ----
    half8 rW2l[2][8];
    {
        const half8* g2l = reinterpret_cast<const half8*>(ws + W2L_OFF);
        #pragma unroll
        for (int kk = 0; kk < 8; ++kk) {
            rW2l[0][kk] = g2l[(kk * 16 + t0n) * 64 + lane];
            rW2l[1][kk] = g2l[(kk * 16 + t1n) * 64 + lane];
        }
    }
    const float rB2a = b2[col0], rB2b = b2[col1];
    const float rB3 = b3[(w < 4) ? ocol : 0];

    // y state in C-frag registers (meaningful on w<4)
    float yv[4];
    #pragma unroll
    for (int r = 0; r < 4; ++r)
        yv[r] = x0[(r0 + q4 + r) * 64 + ((w < 4) ? ocol : 0)];

    // ---- stage u (swizzled, 64-wide) into sA1 temporarily; z-y into sZ ----
    {
        int row = tid >> 5, c0 = (tid & 31) * 2;
        float u0v = u[(r0 + row) * 64 + c0], u1v = u[(r0 + row) * 64 + c0 + 1];
        float y0v = x0[(r0 + row) * 64 + c0], y1v = x0[(r0 + row) * 64 + c0 + 1];
        int idx = (row * 64 + c0) ^ ((row & 7) << 3);
        _Float16 g0 = (_Float16)u0v, g1 = (_Float16)u1v;
        sA1h[idx] = g0; sA1h[idx + 1] = g1;
        sA1l[idx] = (_Float16)(u0v - (float)g0);
        sA1l[idx + 1] = (_Float16)(u1v - (float)g1);
        _Float16 h0 = (_Float16)y0v, h1 = (_Float16)y1v;
        sZh[idx] = h0; sZh[idx + 1] = h1;
        sZl[idx] = (_Float16)(y0v - (float)h0);
        sZl[idx + 1] = (_Float16)(y1v - (float)h1);
    }
    __syncthreads();

    // ---- precompute cU = u @ W1u^T + b1 for both owned tiles (one-time) ----
    float cU[2][4];
    {
        const half8* guh = reinterpret_cast<const half8*>(ws + W1UH_OFF);
        const half8* gul = reinterpret_cast<const half8*>(ws + W1UL_OFF);
        #pragma unroll
        for (int t = 0; t < 2; ++t) {
            int tn = t0n + t;
            float b1v = b1[16 * tn + arow];
            floatx4 a0 = floatx4{b1v, b1v, b1v, b1v};
            floatx4 a1v = floatx4{0.f, 0.f, 0.f, 0.f};
            #pragma unroll
            for (int kk = 0; kk < 2; ++kk) {
                half8 ah = lds_frag(sA1h, 64, arow, kb + kk * 32);
                half8 al = lds_frag(sA1l, 64, arow, kb + kk * 32);
                half8 bh = guh[(kk * 16 + tn) * 64 + lane];
                half8 bl = gul[(kk * 16 + tn) * 64 + lane];
                floatx4& ac = kk ? a1v : a0;
                ac = mfma16(ah, bh, ac);
                ac = mfma16(ah, bl, ac);
                ac = mfma16(al, bh, ac);
            }
            #pragma unroll
            for (int r = 0; r < 4; ++r) cU[t][r] = a0[r] + a1v[r];
        }
    }
    __syncthreads();  // done using sA1 as u-staging

    const int nsteps = (t1p[0] - t0p[0]) * 60;  // h = 60s = 1/60 hr
    const float H = 1.0f / 60.0f;
    const half8* g2h = reinterpret_cast<const half8*>(ws + W2H_OFF);
    const half8* g1yl = reinterpret_cast<const half8*>(ws + W1YL_OFF);

    constexpr float CF[6][6] = {
        {0.161f, 0.f, 0.f, 0.f, 0.f, 0.f},
        {-0.008480655492356989f, 0.335480655492357f, 0.f, 0.f, 0.f, 0.f},
        {2.8971530571054935f, -6.359448489975075f, 4.3622954328695815f, 0.f, 0.f, 0.f},
        {5.325864828439257f, -11.748883564062828f, 7.4955393428898365f, -0.09249506636175525f, 0.f, 0.f},
        {5.86145544294642f, -12.92096931784711f, 8.159367898576159f, -0.071584973281401f, -0.028269050394068383f, 0.f},
        {0.09646076681806523f, 0.01f, 0.4798896504144996f, 1.379008574103742f, -3.290069515436081f, 2.324710524099774f},
    };

    // W1y-lo stream buffer (reloaded each stage during phase C)
    half8 w1l[2][2];
    #pragma unroll
    for (int t = 0; t < 2; ++t)
        #pragma unroll
        for (int kk = 0; kk < 2; ++kk)
            w1l[t][kk] = g1yl[(kk * 16 + t0n + t) * 64 + lane];

    #pragma unroll 1
    for (int step = 0; step < nsteps; ++step) {
        #pragma unroll
        for (int stg = 0; stg < 6; ++stg) {
            // ---------- Phase A: L1 (z_y @ W1y^T + cU -> relu -> sA1) ----------
            // issue W2h prefetch for L2's kk=0 first (hides under L1 compute)
            half8 pf0 = g2h[(0 * 16 + t0n) * 64 + lane];
            half8 pf1 = g2h[(0 * 16 + t1n) * 64 + lane];
            #pragma unroll
            for (int t = 0; t < 2; ++t) {
                floatx4 a0 = floatx4{cU[t][0], cU[t][1], cU[t][2], cU[t][3]};
                floatx4 a1v = floatx4{0.f, 0.f, 0.f, 0.f};
                #pragma unroll
                for (int kk = 0; kk < 2; ++kk) {
                    half8 ah = lds_frag(sZh, 64, arow, kb + kk * 32);
                    half8 al = lds_frag(sZl, 64, arow, kb + kk * 32);
                    half8 bh = *reinterpret_cast<const half8*>(
                        sW1yh + ((kk * 16 + t0n + t) * 64 + lane) * 8);
                    floatx4& ac = kk ? a1v : a0;
                    ac = mfma16(ah, bh, ac);
                    ac = mfma16(ah, w1l[t][kk], ac);
                    ac = mfma16(al, bh, ac);
                }
                int col = 16 * (t0n + t) + arow;
                #pragma unroll
                for (int r = 0; r < 4; ++r) {
                    int orow = q4 + r;
                    float v = fmaxf(a0[r] + a1v[r], 0.f);
                    _Float16 hi = (_Float16)v, lo = (_Float16)(v - (float)hi);
                    int idx = (orow * 256 + col) ^ ((orow & 7) << 3);
                    sA1h[idx] = hi;
                    sA1l[idx] = lo;
                }
            }
            __syncthreads();
            // ---------- Phase B: L2 (a1 @ W2^T -> relu -> sA2), W2h depth-1 prefetch ----------
            {
                floatx4 acc[2][2];
                acc[0][0] = floatx4{rB2a, rB2a, rB2a, rB2a};
                acc[0][1] = floatx4{0.f, 0.f, 0.f, 0.f};
                acc[1][0] = floatx4{rB2b, rB2b, rB2b, rB2b};
                acc[1][1] = floatx4{0.f, 0.f, 0.f, 0.f};
                #pragma unroll
                for (int kk = 0; kk < 8; ++kk) {
                    half8 c0v = pf0, c1v = pf1;
                    if (kk < 7) {
                        pf0 = g2h[((kk + 1) * 16 + t0n) * 64 + lane];
                        pf1 = g2h[((kk + 1) * 16 + t1n) * 64 + lane];
                    }
                    half8 ah = lds_frag(sA1h, 256, arow, kb + kk * 32);
                    half8 al = lds_frag(sA1l, 256, arow, kb + kk * 32);
                    acc[0][kk & 1] = mfma16(ah, c0v, acc[0][kk & 1]);
                    acc[0][kk & 1] = mfma16(ah, rW2l[0][kk], acc[0][kk & 1]);
                    acc[0][kk & 1] = mfma16(al, c0v, acc[0][kk & 1]);
                    acc[1][kk & 1] = mfma16(ah, c1v, acc[1][kk & 1]);
                    acc[1][kk & 1] = mfma16(ah, rW2l[1][kk], acc[1][kk & 1]);
                    acc[1][kk & 1] = mfma16(al, c1v, acc[1][kk & 1]);
                }
                #pragma unroll
                for (int t = 0; t < 2; ++t) {
                    int col = 16 * (t0n + t) + arow;
                    #pragma unroll
                    for (int r = 0; r < 4; ++r) {
                        int orow = q4 + r;
                        float v = fmaxf(acc[t][0][r] + acc[t][1][r], 0.f);
                        _Float16 hi = (_Float16)v, lo = (_Float16)(v - (float)hi);
                        int idx = (orow * 256 + col) ^ ((orow & 7) << 3);
                        sA2h[idx] = hi;
                        sA2l[idx] = lo;
                    }
                }
            }
            __syncthreads();
            // ---------- Phase C: L3 + combine (waves 0-3); all waves reload W1y-lo ----------
            #pragma unroll
            for (int t = 0; t < 2; ++t)
                #pragma unroll
                for (int kk = 0; kk < 2; ++kk)
                    w1l[t][kk] = g1yl[(kk * 16 + t0n + t) * 64 + lane];
            if (w < 4) {
                floatx4 aE = floatx4{rB3, rB3, rB3, rB3};
                floatx4 aO = floatx4{0.f, 0.f, 0.f, 0.f};
                #pragma unroll
                for (int kk = 0; kk < 8; ++kk) {
                    half8 ah = lds_frag(sA2h, 256, arow, kb + kk * 32);
                    half8 al = lds_frag(sA2l, 256, arow, kb + kk * 32);
                    half8 bh = *reinterpret_cast<const half8*>(
                        sW3h + ((kk * 4 + w) * 64 + lane) * 8);
                    half8 bl = *reinterpret_cast<const half8*>(
                        sW3l + ((kk * 4 + w) * 64 + lane) * 8);
                    floatx4& ac = (kk & 1) ? aO : aE;
                    ac = mfma16(ah, bh, ac);
                    ac = mfma16(ah, bl, ac);
                    ac = mfma16(al, bh, ac);
                }
                // combine: z = y + H*(sum_{j<stg} c_j*k_j + c_stg*k_new)
                #pragma unroll
                for (int r = 0; r < 4; ++r) {
                    int orow = q4 + r;
                    float kc = aE[r] + aO[r];
                    float s = CF[stg][stg] * kc;
                    #pragma unroll
                    for (int j = 0; j < stg; ++j)
                        s += CF[stg][j] * sKf[j * 1024 + orow * 64 + ocol];
                    float z = yv[r] + H * s;
                    if (stg < 5) sKf[stg * 1024 + orow * 64 + ocol] = kc;
                    else yv[r] = z;  // final combine of the step
                    int idx = (orow * 64 + ocol) ^ ((orow & 7) << 3);
                    _Float16 h0 = (_Float16)z;
                    sZh[idx] = h0;
                    sZl[idx] = (_Float16)(z - (float)h0);
                }
            }
            __syncthreads();
        }
    }
    // ---- write y_final from registers ----
    if (w < 4) {
        #pragma unroll
        for (int r = 0; r < 4; ++r)
            out[(r0 + q4 + r) * 64 + ocol] = yv[r];
    }
}

extern "C" void kernel_launch(void* const* d_in, const int* in_sizes, int n_in,
                              void* d_out, int out_size, void* d_ws, size_t ws_size,
                              hipStream_t stream)
{
    const float* x0 = (const float*)d_in[0];
    const float* u  = (const float*)d_in[1];
    const float* W1 = (const float*)d_in[2];
    const float* b1 = (const float*)d_in[3];
    const float* W2 = (const float*)d_in[4];
    const float* b2 = (const float*)d_in[5];
    const float* W3 = (const float*)d_in[6];
    const float* b3 = (const float*)d_in[7];
    const int* t0 = (const int*)d_in[8];
    const int* t1 = (const int*)d_in[9];
    float* out = (float*)d_out;
    _Float16* ws = (_Float16*)d_ws;

    pack_weights<<<448, 256, 0, stream>>>(W1, W2, W3, ws);
    ode_kernel<<<64, 512, 0, stream>>>(x0, u, b1, b2, b3, ws, t0, t1, out);
}